// Round 4
// baseline (83.142 us; speedup 1.0000x reference)
//
#include <hip/hip_runtime.h>
#include <math.h>

#define D 512
#define KP 1024            // packed K: A=[q_hi | q_lo], B=[r_hi | r_hi]
#define NREL 512
#define NB 1024
#define NBLK 256

typedef short bf16x8 __attribute__((ext_vector_type(8)));
typedef float f32x4 __attribute__((ext_vector_type(4)));
typedef unsigned short u16x8 __attribute__((ext_vector_type(8)));

__device__ __forceinline__ unsigned short f2bf(float f) {
    unsigned int u = __float_as_uint(f);
    return (unsigned short)((u + 0x7fffu + ((u >> 16) & 1u)) >> 16);
}
__device__ __forceinline__ float bf2f(unsigned short h) {
    return __uint_as_float(((unsigned int)h) << 16);
}
__device__ __forceinline__ float wave_sum(float v) {
#pragma unroll
    for (int m = 1; m < 64; m <<= 1) v += __shfl_xor(v, m, 64);
    return v;
}

__global__ __launch_bounds__(256) void fused_kernel(
        const float* __restrict__ ent, const float* __restrict__ rel,
        const int* __restrict__ trip, const float* __restrict__ grot,
        const float* __restrict__ bias, float* __restrict__ out,
        unsigned short* __restrict__ A3, unsigned short* __restrict__ B3,
        float* __restrict__ x2, float* __restrict__ y2,
        unsigned int* __restrict__ cnt) {
    const int t = threadIdx.x, wid = t >> 6, lane = t & 63;
    const int W = blockIdx.x * 4 + wid;          // 0..1023 global wave id
    const float c = 0.01f, sc = 0.1f;

    // ================= phase 1: build A3/B3/x2/y2 (wave per row) ============
    if (W < NREL) {                              // rel_hyp row W -> B3 [hi|hi]
        const float* src = rel + (size_t)W * D + lane * 8;
        const float4 u0 = *(const float4*)src;
        const float4 u1 = *(const float4*)(src + 4);
        const float uu = wave_sum(u0.x*u0.x + u0.y*u0.y + u0.z*u0.z + u0.w*u0.w
                                + u1.x*u1.x + u1.y*u1.y + u1.z*u1.z + u1.w*u1.w);
        const float n  = fmaxf(sqrtf(uu), 1e-15f);
        const float es = tanhf(sc * n) / (sc * n);
        u16x8 h;
        h[0]=f2bf(es*u0.x); h[1]=f2bf(es*u0.y); h[2]=f2bf(es*u0.z); h[3]=f2bf(es*u0.w);
        h[4]=f2bf(es*u1.x); h[5]=f2bf(es*u1.y); h[6]=f2bf(es*u1.z); h[7]=f2bf(es*u1.w);
        unsigned short* dst = B3 + (size_t)W * KP + lane * 8;
        *(u16x8*)dst = h;
        *(u16x8*)(dst + D) = h;
        if (lane == 0) y2[W] = es * es * uu;
    }
    {                                            // query row b -> A3 [hi|lo]
        const int b = (W < NREL) ? (W + NREL) : (W - NREL);
        const int si = trip[3 * b], oi = trip[3 * b + 2];
        const float* ps = ent + (size_t)si * D + lane * 8;
        const float* po = ent + (size_t)oi * D + lane * 8;
        const float4 s0 = *(const float4*)ps, s1 = *(const float4*)(ps + 4);
        const float4 o0 = *(const float4*)po, o1 = *(const float4*)(po + 4);
        const float ss = wave_sum(s0.x*s0.x + s0.y*s0.y + s0.z*s0.z + s0.w*s0.w
                                + s1.x*s1.x + s1.y*s1.y + s1.z*s1.z + s1.w*s1.w);
        const float oo = wave_sum(o0.x*o0.x + o0.y*o0.y + o0.z*o0.z + o0.w*o0.w
                                + o1.x*o1.x + o1.y*o1.y + o1.z*o1.z + o1.w*o1.w);
        const float n_s = fmaxf(sqrtf(ss), 1e-15f);
        const float arg = fminf(fmaxf(sc * n_s, -1.0f + 1e-7f), 1.0f - 1e-7f);
        const float ls  = atanhf(arg) / (sc * n_s);
        // givens rotation of x = ls*s  (pairs (2p,2p+1), angle[p], p = 4*lane+k)
        const float4 ang = *(const float4*)(grot + 4 * lane);
        float sa0, ca0, sa1, ca1, sa2, ca2, sa3, ca3;
        sincosf(ang.x, &sa0, &ca0); sincosf(ang.y, &sa1, &ca1);
        sincosf(ang.z, &sa2, &ca2); sincosf(ang.w, &sa3, &ca3);
        const float x0 = ls*s0.x, x1 = ls*s0.y, x2v = ls*s0.z, x3 = ls*s0.w;
        const float x4 = ls*s1.x, x5 = ls*s1.y, x6 = ls*s1.z, x7 = ls*s1.w;
        const float ux0 = ca0*x0 - sa0*x1, uy0 = sa0*x0 + ca0*x1;
        const float ux1 = ca1*x2v - sa1*x3, uy1 = sa1*x2v + ca1*x3;
        const float ux2 = ca2*x4 - sa2*x5, uy2 = sa2*x4 + ca2*x5;
        const float ux3 = ca3*x6 - sa3*x7, uy3 = sa3*x6 + ca3*x7;
        const float uo = wave_sum(ux0*o0.x + uy0*o0.y + ux1*o0.z + uy1*o0.w
                                + ux2*o1.x + uy2*o1.y + ux3*o1.z + uy3*o1.w);
        // ||u|| = ls*||s|| (rotation orthogonal); ||es*u|| = es*||u||
        const float n_u = ls * n_s;
        const float tt  = tanhf(sc * n_u);
        const float es  = tt / (sc * n_u);
        const float rn  = tt / sc;               // es * n_u
        const float rr  = rn * rn;
        const float ro  = es * uo;
        const float A1  = 1.0f - 2.0f*c*ro + c*oo;
        const float B1  = 1.0f - c*rr;
        const float den = fmaxf(1.0f - 2.0f*c*ro + c*c*rr*oo, 1e-15f);
        const float inv = 1.0f / den;
        const float qa  = -A1 * es * inv, qb = B1 * inv;
        float q[8] = { qa*ux0 + qb*o0.x, qa*uy0 + qb*o0.y,
                       qa*ux1 + qb*o0.z, qa*uy1 + qb*o0.w,
                       qa*ux2 + qb*o1.x, qa*uy2 + qb*o1.y,
                       qa*ux3 + qb*o1.z, qa*uy3 + qb*o1.w };
        u16x8 hi, lo;
#pragma unroll
        for (int i = 0; i < 8; ++i) {
            hi[i] = f2bf(q[i]);
            lo[i] = f2bf(q[i] - bf2f(hi[i]));
        }
        unsigned short* dst = A3 + (size_t)b * KP + lane * 8;
        *(u16x8*)dst = hi;
        *(u16x8*)(dst + D) = lo;
        if (lane == 0)
            x2[b] = (A1*A1*rr - 2.0f*A1*B1*ro + B1*B1*oo) * inv * inv;
    }

    // ================= grid-wide barrier (device-scope, capture-safe) =======
    __threadfence();
    __syncthreads();
    if (t == 0) {
        __hip_atomic_fetch_add(cnt, 1u, __ATOMIC_RELEASE, __HIP_MEMORY_SCOPE_AGENT);
        while (__hip_atomic_load(cnt, __ATOMIC_ACQUIRE, __HIP_MEMORY_SCOPE_AGENT) < NBLK)
            __builtin_amdgcn_s_sleep(2);
    }
    __syncthreads();
    __threadfence();

    // ================= phase 2: score GEMM + epilogue =======================
    // 512 tiles of 32x32; block bid handles tiles 2*bid, 2*bid+1;
    // wave pair splits K (khalf), combined via LDS.
    const int tsel = wid >> 1, khalf = wid & 1;
    const int T = blockIdx.x * 2 + tsel;
    const int m0 = (T >> 4) * 32, n0 = (T & 15) * 32;
    const int row = lane & 15, kg = lane >> 4;

    const bf16x8* pa0 = (const bf16x8*)(A3 + (size_t)(m0 + row) * KP) + kg;
    const bf16x8* pa1 = (const bf16x8*)(A3 + (size_t)(m0 + 16 + row) * KP) + kg;
    const bf16x8* pb0 = (const bf16x8*)(B3 + (size_t)(n0 + row) * KP) + kg;
    const bf16x8* pb1 = (const bf16x8*)(B3 + (size_t)(n0 + 16 + row) * KP) + kg;

    f32x4 acc[2][2] = {};
    const int k8end = khalf * 64 + 64;
#pragma unroll 4
    for (int k8 = khalf * 64; k8 < k8end; k8 += 4) {
        const bf16x8 a0 = pa0[k8], a1 = pa1[k8];
        const bf16x8 b0 = pb0[k8], b1 = pb1[k8];
        acc[0][0] = __builtin_amdgcn_mfma_f32_16x16x32_bf16(a0, b0, acc[0][0], 0, 0, 0);
        acc[0][1] = __builtin_amdgcn_mfma_f32_16x16x32_bf16(a0, b1, acc[0][1], 0, 0, 0);
        acc[1][0] = __builtin_amdgcn_mfma_f32_16x16x32_bf16(a1, b0, acc[1][0], 0, 0, 0);
        acc[1][1] = __builtin_amdgcn_mfma_f32_16x16x32_bf16(a1, b1, acc[1][1], 0, 0, 0);
    }

    __shared__ f32x4 lacc[2][64][4];
    if (khalf == 1) {
#pragma unroll
        for (int i = 0; i < 2; ++i)
#pragma unroll
            for (int j = 0; j < 2; ++j) lacc[tsel][lane][i * 2 + j] = acc[i][j];
    }
    __syncthreads();
    if (khalf == 0) {
#pragma unroll
        for (int i = 0; i < 2; ++i)
#pragma unroll
            for (int j = 0; j < 2; ++j) acc[i][j] += lacc[tsel][lane][i * 2 + j];

        // C/D layout: col = lane&15, row = (lane>>4)*4 + reg
        const int crow = (lane >> 4) * 4;
        const int ccol = lane & 15;
#pragma unroll
        for (int i = 0; i < 2; ++i) {
#pragma unroll
            for (int r = 0; r < 4; ++r) {
                const int m = m0 + i * 16 + crow + r;
                const float X2 = x2[m];
                const float B1 = 1.0f - c * X2;
#pragma unroll
                for (int j = 0; j < 2; ++j) {
                    const int n  = n0 + j * 16 + ccol;
                    const float qd = acc[i][j][r];
                    const float Y2 = y2[n];
                    const float A1  = 1.0f - 2.0f * c * qd + c * Y2;
                    const float den = fmaxf(1.0f - 2.0f * c * qd + c * c * X2 * Y2, 1e-15f);
                    const float num2 = A1 * A1 * X2 - 2.0f * A1 * B1 * qd + B1 * B1 * Y2;
                    out[(size_t)m * NREL + n] = -(num2 / (den * den)) + bias[n];
                }
            }
        }
    }
}

extern "C" void kernel_launch(void* const* d_in, const int* in_sizes, int n_in,
                              void* d_out, int out_size, void* d_ws, size_t ws_size,
                              hipStream_t stream) {
    const float* ent  = (const float*)d_in[0];   // (20000, 512)
    const float* rel  = (const float*)d_in[1];   // (512, 512)
    const int*   trip = (const int*)d_in[2];     // (1024, 3)
    const float* grot = (const float*)d_in[3];   // (256,)
    const float* bias = (const float*)d_in[4];   // (512,)
    float* out = (float*)d_out;                  // (1024, 512)

    unsigned int*   cnt = (unsigned int*)d_ws;
    unsigned short* A3  = (unsigned short*)((char*)d_ws + 256); // 1024*1024 bf16
    unsigned short* B3  = A3 + (size_t)NB * KP;                 // 512*1024 bf16
    float* x2 = (float*)(B3 + (size_t)NREL * KP);
    float* y2 = x2 + NB;

    hipMemsetAsync(d_ws, 0, 4, stream);          // reset barrier counter
    fused_kernel<<<dim3(NBLK), dim3(256), 0, stream>>>(
        ent, rel, trip, grot, bias, out, A3, B3, x2, y2, cnt);
}

// Round 5
// 21.539 us; speedup vs baseline: 3.8601x; 3.8601x over previous
//
#include <hip/hip_runtime.h>
#include <math.h>

#define D 512
#define KP 1024            // packed K: A=[q_hi | q_lo], B=[r_hi | r_hi]
#define NREL 512
#define NB 1024

typedef short bf16x8 __attribute__((ext_vector_type(8)));
typedef float f32x4 __attribute__((ext_vector_type(4)));
typedef unsigned short u16x8 __attribute__((ext_vector_type(8)));

__device__ __forceinline__ unsigned short f2bf(float f) {
    unsigned int u = __float_as_uint(f);
    return (unsigned short)((u + 0x7fffu + ((u >> 16) & 1u)) >> 16);
}
__device__ __forceinline__ float bf2f(unsigned short h) {
    return __uint_as_float(((unsigned int)h) << 16);
}
__device__ __forceinline__ float wave_sum(float v) {
#pragma unroll
    for (int m = 1; m < 64; m <<= 1) v += __shfl_xor(v, m, 64);
    return v;
}

// ---- prep: one wave per row; shuffle-only reductions -----------------------
// waves 0..511  -> rel_hyp row W    -> B3 [hi|hi], y2
// waves 512..1535 -> query row W-512 -> A3 [hi|lo], x2
__global__ __launch_bounds__(256) void prep_kernel(
        const float* __restrict__ ent, const float* __restrict__ rel,
        const int* __restrict__ trip, const float* __restrict__ grot,
        unsigned short* __restrict__ A3, unsigned short* __restrict__ B3,
        float* __restrict__ x2, float* __restrict__ y2) {
    const int t = threadIdx.x, wid = t >> 6, lane = t & 63;
    const int W = blockIdx.x * 4 + wid;
    const float c = 0.01f, sc = 0.1f;

    if (W < NREL) {
        const float* src = rel + (size_t)W * D + lane * 8;
        const float4 u0 = *(const float4*)src;
        const float4 u1 = *(const float4*)(src + 4);
        const float uu = wave_sum(u0.x*u0.x + u0.y*u0.y + u0.z*u0.z + u0.w*u0.w
                                + u1.x*u1.x + u1.y*u1.y + u1.z*u1.z + u1.w*u1.w);
        const float n  = fmaxf(sqrtf(uu), 1e-15f);
        const float es = tanhf(sc * n) / (sc * n);
        u16x8 h;
        h[0]=f2bf(es*u0.x); h[1]=f2bf(es*u0.y); h[2]=f2bf(es*u0.z); h[3]=f2bf(es*u0.w);
        h[4]=f2bf(es*u1.x); h[5]=f2bf(es*u1.y); h[6]=f2bf(es*u1.z); h[7]=f2bf(es*u1.w);
        unsigned short* dst = B3 + (size_t)W * KP + lane * 8;
        *(u16x8*)dst = h;
        *(u16x8*)(dst + D) = h;
        if (lane == 0) y2[W] = es * es * uu;
    } else {
        const int b = W - NREL;
        const int si = trip[3 * b], oi = trip[3 * b + 2];
        const float* ps = ent + (size_t)si * D + lane * 8;
        const float* po = ent + (size_t)oi * D + lane * 8;
        const float4 s0 = *(const float4*)ps, s1 = *(const float4*)(ps + 4);
        const float4 o0 = *(const float4*)po, o1 = *(const float4*)(po + 4);
        const float ss = wave_sum(s0.x*s0.x + s0.y*s0.y + s0.z*s0.z + s0.w*s0.w
                                + s1.x*s1.x + s1.y*s1.y + s1.z*s1.z + s1.w*s1.w);
        const float oo = wave_sum(o0.x*o0.x + o0.y*o0.y + o0.z*o0.z + o0.w*o0.w
                                + o1.x*o1.x + o1.y*o1.y + o1.z*o1.z + o1.w*o1.w);
        const float n_s = fmaxf(sqrtf(ss), 1e-15f);
        const float arg = fminf(fmaxf(sc * n_s, -1.0f + 1e-7f), 1.0f - 1e-7f);
        const float ls  = atanhf(arg) / (sc * n_s);
        const float4 ang = *(const float4*)(grot + 4 * lane);
        float sa0, ca0, sa1, ca1, sa2, ca2, sa3, ca3;
        sincosf(ang.x, &sa0, &ca0); sincosf(ang.y, &sa1, &ca1);
        sincosf(ang.z, &sa2, &ca2); sincosf(ang.w, &sa3, &ca3);
        const float x0 = ls*s0.x, x1 = ls*s0.y, x2v = ls*s0.z, x3 = ls*s0.w;
        const float x4 = ls*s1.x, x5 = ls*s1.y, x6 = ls*s1.z, x7 = ls*s1.w;
        const float ux0 = ca0*x0 - sa0*x1, uy0 = sa0*x0 + ca0*x1;
        const float ux1 = ca1*x2v - sa1*x3, uy1 = sa1*x2v + ca1*x3;
        const float ux2 = ca2*x4 - sa2*x5, uy2 = sa2*x4 + ca2*x5;
        const float ux3 = ca3*x6 - sa3*x7, uy3 = sa3*x6 + ca3*x7;
        const float uo = wave_sum(ux0*o0.x + uy0*o0.y + ux1*o0.z + uy1*o0.w
                                + ux2*o1.x + uy2*o1.y + ux3*o1.z + uy3*o1.w);
        // ||u|| = ls*||s|| (rotation orthogonal); ||es*u|| = es*||u||
        const float n_u = ls * n_s;
        const float tt  = tanhf(sc * n_u);
        const float es  = tt / (sc * n_u);
        const float rn  = tt / sc;               // es * n_u
        const float rr  = rn * rn;
        const float ro  = es * uo;
        const float A1  = 1.0f - 2.0f*c*ro + c*oo;
        const float B1  = 1.0f - c*rr;
        const float den = fmaxf(1.0f - 2.0f*c*ro + c*c*rr*oo, 1e-15f);
        const float inv = 1.0f / den;
        const float qa  = -A1 * es * inv, qb = B1 * inv;
        float q[8] = { qa*ux0 + qb*o0.x, qa*uy0 + qb*o0.y,
                       qa*ux1 + qb*o0.z, qa*uy1 + qb*o0.w,
                       qa*ux2 + qb*o1.x, qa*uy2 + qb*o1.y,
                       qa*ux3 + qb*o1.z, qa*uy3 + qb*o1.w };
        u16x8 hi, lo;
#pragma unroll
        for (int i = 0; i < 8; ++i) {
            hi[i] = f2bf(q[i]);
            lo[i] = f2bf(q[i] - bf2f(hi[i]));
        }
        unsigned short* dst = A3 + (size_t)b * KP + lane * 8;
        *(u16x8*)dst = hi;
        *(u16x8*)(dst + D) = lo;
        if (lane == 0)
            x2[b] = (A1*A1*rr - 2.0f*A1*B1*ro + B1*B1*oo) * inv * inv;
    }
}

// ---- score: 64x32 tile / 256-thr block; 4 waves = 2 row-halves x 2 K-halves
__global__ __launch_bounds__(256) void score_mfma(
        const ushort* __restrict__ A3, const ushort* __restrict__ B3,
        const float* __restrict__ x2, const float* __restrict__ y2,
        const float* __restrict__ bias, float* __restrict__ out) {
    const int t = threadIdx.x, wid = t >> 6, lane = t & 63;
    const int wm = wid & 1, kh = wid >> 1;
    const int m0 = blockIdx.y * 64 + wm * 32;
    const int n0 = blockIdx.x * 32;
    const int row = lane & 15, kg = lane >> 4;

    const bf16x8* pa0 = (const bf16x8*)(A3 + (size_t)(m0 + row) * KP) + kg;
    const bf16x8* pa1 = (const bf16x8*)(A3 + (size_t)(m0 + 16 + row) * KP) + kg;
    const bf16x8* pb0 = (const bf16x8*)(B3 + (size_t)(n0 + row) * KP) + kg;
    const bf16x8* pb1 = (const bf16x8*)(B3 + (size_t)(n0 + 16 + row) * KP) + kg;

    f32x4 acc[2][2] = {};
    const int k8beg = kh * 64, k8end = k8beg + 64;
#pragma unroll 4
    for (int k8 = k8beg; k8 < k8end; k8 += 4) {
        const bf16x8 a0 = pa0[k8], a1 = pa1[k8];
        const bf16x8 b0 = pb0[k8], b1 = pb1[k8];
        acc[0][0] = __builtin_amdgcn_mfma_f32_16x16x32_bf16(a0, b0, acc[0][0], 0, 0, 0);
        acc[0][1] = __builtin_amdgcn_mfma_f32_16x16x32_bf16(a0, b1, acc[0][1], 0, 0, 0);
        acc[1][0] = __builtin_amdgcn_mfma_f32_16x16x32_bf16(a1, b0, acc[1][0], 0, 0, 0);
        acc[1][1] = __builtin_amdgcn_mfma_f32_16x16x32_bf16(a1, b1, acc[1][1], 0, 0, 0);
    }

    __shared__ f32x4 lacc[2][64][4];
    if (kh == 1) {
#pragma unroll
        for (int i = 0; i < 2; ++i)
#pragma unroll
            for (int j = 0; j < 2; ++j) lacc[wm][lane][i * 2 + j] = acc[i][j];
    }
    __syncthreads();
    if (kh == 0) {
#pragma unroll
        for (int i = 0; i < 2; ++i)
#pragma unroll
            for (int j = 0; j < 2; ++j) acc[i][j] += lacc[wm][lane][i * 2 + j];

        // C/D layout: col = lane&15, row = (lane>>4)*4 + reg
        const float c = 0.01f;
        const int crow = (lane >> 4) * 4;
        const int ccol = lane & 15;
#pragma unroll
        for (int i = 0; i < 2; ++i) {
#pragma unroll
            for (int r = 0; r < 4; ++r) {
                const int m = m0 + i * 16 + crow + r;
                const float X2 = x2[m];
                const float B1 = 1.0f - c * X2;
#pragma unroll
                for (int j = 0; j < 2; ++j) {
                    const int n  = n0 + j * 16 + ccol;
                    const float qd = acc[i][j][r];
                    const float Y2 = y2[n];
                    const float A1  = 1.0f - 2.0f * c * qd + c * Y2;
                    const float den = fmaxf(1.0f - 2.0f * c * qd + c * c * X2 * Y2, 1e-15f);
                    const float num2 = A1 * A1 * X2 - 2.0f * A1 * B1 * qd + B1 * B1 * Y2;
                    out[(size_t)m * NREL + n] = -(num2 / (den * den)) + bias[n];
                }
            }
        }
    }
}

extern "C" void kernel_launch(void* const* d_in, const int* in_sizes, int n_in,
                              void* d_out, int out_size, void* d_ws, size_t ws_size,
                              hipStream_t stream) {
    const float* ent  = (const float*)d_in[0];   // (20000, 512)
    const float* rel  = (const float*)d_in[1];   // (512, 512)
    const int*   trip = (const int*)d_in[2];     // (1024, 3)
    const float* grot = (const float*)d_in[3];   // (256,)
    const float* bias = (const float*)d_in[4];   // (512,)
    float* out = (float*)d_out;                  // (1024, 512)

    unsigned short* A3 = (unsigned short*)d_ws;          // 1024*1024 bf16
    unsigned short* B3 = A3 + (size_t)NB * KP;           // 512*1024 bf16
    float* x2 = (float*)(B3 + (size_t)NREL * KP);
    float* y2 = x2 + NB;

    prep_kernel<<<dim3((NREL + NB) / 4), dim3(256), 0, stream>>>(
        ent, rel, trip, grot, A3, B3, x2, y2);
    score_mfma<<<dim3(NREL / 32, NB / 64), dim3(256), 0, stream>>>(
        A3, B3, x2, y2, bias, out);
}

// Round 6
// 16.973 us; speedup vs baseline: 4.8985x; 1.2690x over previous
//
#include <hip/hip_runtime.h>
#include <math.h>

#define D 512
#define KP 512             // single-precision fp16 GEMM: A=[q], B=[r]
#define NREL 512
#define NB 1024

typedef _Float16 f16x8 __attribute__((ext_vector_type(8)));
typedef float f32x4 __attribute__((ext_vector_type(4)));

__device__ __forceinline__ float wave_sum(float v) {
#pragma unroll
    for (int m = 1; m < 64; m <<= 1) v += __shfl_xor(v, m, 64);
    return v;
}

// ---- prep: one wave per row; shuffle-only reductions -----------------------
// waves 0..511    -> rel_hyp row W   -> B3 (fp16), y2
// waves 512..1535 -> query row W-512 -> A3 (fp16), x2
__global__ __launch_bounds__(256) void prep_kernel(
        const float* __restrict__ ent, const float* __restrict__ rel,
        const int* __restrict__ trip, const float* __restrict__ grot,
        _Float16* __restrict__ A3, _Float16* __restrict__ B3,
        float* __restrict__ x2, float* __restrict__ y2) {
    const int t = threadIdx.x, wid = t >> 6, lane = t & 63;
    const int W = blockIdx.x * 4 + wid;
    const float c = 0.01f, sc = 0.1f;

    if (W < NREL) {
        const float* src = rel + (size_t)W * D + lane * 8;
        const float4 u0 = *(const float4*)src;
        const float4 u1 = *(const float4*)(src + 4);
        const float uu = wave_sum(u0.x*u0.x + u0.y*u0.y + u0.z*u0.z + u0.w*u0.w
                                + u1.x*u1.x + u1.y*u1.y + u1.z*u1.z + u1.w*u1.w);
        const float n  = fmaxf(sqrtf(uu), 1e-15f);
        const float es = tanhf(sc * n) / (sc * n);
        f16x8 h;
        h[0] = (_Float16)(es*u0.x); h[1] = (_Float16)(es*u0.y);
        h[2] = (_Float16)(es*u0.z); h[3] = (_Float16)(es*u0.w);
        h[4] = (_Float16)(es*u1.x); h[5] = (_Float16)(es*u1.y);
        h[6] = (_Float16)(es*u1.z); h[7] = (_Float16)(es*u1.w);
        *(f16x8*)(B3 + (size_t)W * KP + lane * 8) = h;
        if (lane == 0) y2[W] = es * es * uu;
    } else {
        const int b = W - NREL;
        const int si = trip[3 * b], oi = trip[3 * b + 2];
        const float* ps = ent + (size_t)si * D + lane * 8;
        const float* po = ent + (size_t)oi * D + lane * 8;
        const float4 s0 = *(const float4*)ps, s1 = *(const float4*)(ps + 4);
        const float4 o0 = *(const float4*)po, o1 = *(const float4*)(po + 4);
        const float ss = wave_sum(s0.x*s0.x + s0.y*s0.y + s0.z*s0.z + s0.w*s0.w
                                + s1.x*s1.x + s1.y*s1.y + s1.z*s1.z + s1.w*s1.w);
        const float oo = wave_sum(o0.x*o0.x + o0.y*o0.y + o0.z*o0.z + o0.w*o0.w
                                + o1.x*o1.x + o1.y*o1.y + o1.z*o1.z + o1.w*o1.w);
        const float n_s = fmaxf(sqrtf(ss), 1e-15f);
        const float arg = fminf(fmaxf(sc * n_s, -1.0f + 1e-7f), 1.0f - 1e-7f);
        const float ls  = atanhf(arg) / (sc * n_s);
        const float4 ang = *(const float4*)(grot + 4 * lane);
        float sa0, ca0, sa1, ca1, sa2, ca2, sa3, ca3;
        sincosf(ang.x, &sa0, &ca0); sincosf(ang.y, &sa1, &ca1);
        sincosf(ang.z, &sa2, &ca2); sincosf(ang.w, &sa3, &ca3);
        const float x0 = ls*s0.x, x1 = ls*s0.y, x2v = ls*s0.z, x3 = ls*s0.w;
        const float x4 = ls*s1.x, x5 = ls*s1.y, x6 = ls*s1.z, x7 = ls*s1.w;
        const float ux0 = ca0*x0 - sa0*x1, uy0 = sa0*x0 + ca0*x1;
        const float ux1 = ca1*x2v - sa1*x3, uy1 = sa1*x2v + ca1*x3;
        const float ux2 = ca2*x4 - sa2*x5, uy2 = sa2*x4 + ca2*x5;
        const float ux3 = ca3*x6 - sa3*x7, uy3 = sa3*x6 + ca3*x7;
        const float uo = wave_sum(ux0*o0.x + uy0*o0.y + ux1*o0.z + uy1*o0.w
                                + ux2*o1.x + uy2*o1.y + ux3*o1.z + uy3*o1.w);
        // ||u|| = ls*||s|| (rotation orthogonal); ||es*u|| = es*||u||
        const float n_u = ls * n_s;
        const float tt  = tanhf(sc * n_u);
        const float es  = tt / (sc * n_u);
        const float rn  = tt / sc;               // es * n_u
        const float rr  = rn * rn;
        const float ro  = es * uo;
        const float A1  = 1.0f - 2.0f*c*ro + c*oo;
        const float B1  = 1.0f - c*rr;
        const float den = fmaxf(1.0f - 2.0f*c*ro + c*c*rr*oo, 1e-15f);
        const float inv = 1.0f / den;
        const float qa  = -A1 * es * inv, qb = B1 * inv;
        f16x8 h;
        h[0] = (_Float16)(qa*ux0 + qb*o0.x); h[1] = (_Float16)(qa*uy0 + qb*o0.y);
        h[2] = (_Float16)(qa*ux1 + qb*o0.z); h[3] = (_Float16)(qa*uy1 + qb*o0.w);
        h[4] = (_Float16)(qa*ux2 + qb*o1.x); h[5] = (_Float16)(qa*uy2 + qb*o1.y);
        h[6] = (_Float16)(qa*ux3 + qb*o1.z); h[7] = (_Float16)(qa*uy3 + qb*o1.w);
        *(f16x8*)(A3 + (size_t)b * KP + lane * 8) = h;
        if (lane == 0)
            x2[b] = (A1*A1*rr - 2.0f*A1*B1*ro + B1*B1*oo) * inv * inv;
    }
}

// ---- score: 64x32 tile / 256-thr block; 4 waves = 2 row-halves x 2 K-halves
__global__ __launch_bounds__(256) void score_mfma(
        const _Float16* __restrict__ A3, const _Float16* __restrict__ B3,
        const float* __restrict__ x2, const float* __restrict__ y2,
        const float* __restrict__ bias, float* __restrict__ out) {
    const int t = threadIdx.x, wid = t >> 6, lane = t & 63;
    const int wm = wid & 1, kh = wid >> 1;
    const int m0 = blockIdx.y * 64 + wm * 32;
    const int n0 = blockIdx.x * 32;
    const int row = lane & 15, kg = lane >> 4;

    const f16x8* pa0 = (const f16x8*)(A3 + (size_t)(m0 + row) * KP) + kg;
    const f16x8* pa1 = (const f16x8*)(A3 + (size_t)(m0 + 16 + row) * KP) + kg;
    const f16x8* pb0 = (const f16x8*)(B3 + (size_t)(n0 + row) * KP) + kg;
    const f16x8* pb1 = (const f16x8*)(B3 + (size_t)(n0 + 16 + row) * KP) + kg;

    f32x4 acc[2][2] = {};
    const int k8beg = kh * 32, k8end = k8beg + 32;   // half of 64 blocks of 8
#pragma unroll 4
    for (int k8 = k8beg; k8 < k8end; k8 += 4) {
        const f16x8 a0 = pa0[k8], a1 = pa1[k8];
        const f16x8 b0 = pb0[k8], b1 = pb1[k8];
        acc[0][0] = __builtin_amdgcn_mfma_f32_16x16x32_f16(a0, b0, acc[0][0], 0, 0, 0);
        acc[0][1] = __builtin_amdgcn_mfma_f32_16x16x32_f16(a0, b1, acc[0][1], 0, 0, 0);
        acc[1][0] = __builtin_amdgcn_mfma_f32_16x16x32_f16(a1, b0, acc[1][0], 0, 0, 0);
        acc[1][1] = __builtin_amdgcn_mfma_f32_16x16x32_f16(a1, b1, acc[1][1], 0, 0, 0);
    }

    __shared__ f32x4 lacc[2][64][4];
    if (kh == 1) {
#pragma unroll
        for (int i = 0; i < 2; ++i)
#pragma unroll
            for (int j = 0; j < 2; ++j) lacc[wm][lane][i * 2 + j] = acc[i][j];
    }
    __syncthreads();
    if (kh == 0) {
#pragma unroll
        for (int i = 0; i < 2; ++i)
#pragma unroll
            for (int j = 0; j < 2; ++j) acc[i][j] += lacc[wm][lane][i * 2 + j];

        // C/D layout: col = lane&15, row = (lane>>4)*4 + reg
        const float c = 0.01f;
        const int crow = (lane >> 4) * 4;
        const int ccol = lane & 15;
#pragma unroll
        for (int i = 0; i < 2; ++i) {
#pragma unroll
            for (int r = 0; r < 4; ++r) {
                const int m = m0 + i * 16 + crow + r;
                const float X2 = x2[m];
                const float B1 = 1.0f - c * X2;
#pragma unroll
                for (int j = 0; j < 2; ++j) {
                    const int n  = n0 + j * 16 + ccol;
                    const float qd = acc[i][j][r];
                    const float Y2 = y2[n];
                    const float A1  = 1.0f - 2.0f * c * qd + c * Y2;
                    const float den = fmaxf(1.0f - 2.0f * c * qd + c * c * X2 * Y2, 1e-15f);
                    const float num2 = A1 * A1 * X2 - 2.0f * A1 * B1 * qd + B1 * B1 * Y2;
                    out[(size_t)m * NREL + n] = -(num2 / (den * den)) + bias[n];
                }
            }
        }
    }
}

extern "C" void kernel_launch(void* const* d_in, const int* in_sizes, int n_in,
                              void* d_out, int out_size, void* d_ws, size_t ws_size,
                              hipStream_t stream) {
    const float* ent  = (const float*)d_in[0];   // (20000, 512)
    const float* rel  = (const float*)d_in[1];   // (512, 512)
    const int*   trip = (const int*)d_in[2];     // (1024, 3)
    const float* grot = (const float*)d_in[3];   // (256,)
    const float* bias = (const float*)d_in[4];   // (512,)
    float* out = (float*)d_out;                  // (1024, 512)

    _Float16* A3 = (_Float16*)d_ws;              // 1024*512 fp16
    _Float16* B3 = A3 + (size_t)NB * KP;         // 512*512 fp16
    float* x2 = (float*)(B3 + (size_t)NREL * KP);
    float* y2 = x2 + NB;

    prep_kernel<<<dim3((NREL + NB) / 4), dim3(256), 0, stream>>>(
        ent, rel, trip, grot, A3, B3, x2, y2);
    score_mfma<<<dim3(NREL / 32, NB / 64), dim3(256), 0, stream>>>(
        A3, B3, x2, y2, bias, out);
}